// Round 3
// baseline (828.878 us; speedup 1.0000x reference)
//
#include <hip/hip_runtime.h>
#include <hip/hip_bf16.h>
#include <math.h>

#define N_NODES 500000
#define DIM 256
#define ADIM 64
#define NG 512
#define PNB 256   // nodes per k_pool block

typedef __attribute__((ext_vector_type(8))) short short8;
typedef __attribute__((ext_vector_type(4))) float floatx4;

__device__ inline unsigned short f2bf(float f) {
    union { float f; unsigned int u; } v; v.f = f;
    unsigned int u = v.u;
    unsigned int r = u + 0x7FFFu + ((u >> 16) & 1u);   // RNE
    return (unsigned short)(r >> 16);
}

// ---------------- prep: Wt_out[d][o] transpose + bf16 B-fragment table for W_att
// Wbf[((s*4+nt)*64 + quad*16 + lcol)*8 + j] = bf16(W_att[nt*16+lcol][s*32+quad*8+j])
__global__ __launch_bounds__(256) void k_prep(const float* __restrict__ W_att,
                                              const float* __restrict__ W_out,
                                              float* __restrict__ Wt_out,
                                              unsigned short* __restrict__ Wbf) {
    int idx = blockIdx.x * 256 + threadIdx.x;
    if (idx < DIM * DIM) {
        int o = idx / DIM, d = idx % DIM;
        Wt_out[d * DIM + o] = W_out[idx];
    }
    if (idx < ADIM * DIM) {
        int a = idx / DIM, k = idx % DIM;
        int s = k >> 5, quad = (k >> 3) & 3, j = k & 7;
        int nt = a >> 4, lcol = a & 15;
        Wbf[(((s * 4 + nt) * 64) + quad * 16 + lcol) * 8 + j] = f2bf(W_att[idx]);
    }
}

// ---------------- segment offsets from sorted batch ids
__global__ __launch_bounds__(256) void k_offsets(const int* __restrict__ batch,
                                                 int* __restrict__ seg_start) {
    int i = blockIdx.x * 256 + threadIdx.x;
    if (i >= N_NODES) return;
    int b = batch[i];
    if (i == 0) {
        for (int g = 0; g <= b; g++) seg_start[g] = 0;
    } else {
        int pb = batch[i - 1];
        if (pb != b) {
            for (int g = pb + 1; g <= b; g++) seg_start[g] = i;
        }
    }
    if (i == N_NODES - 1) {
        for (int g = b + 1; g <= NG; g++) seg_start[g] = N_NODES;
    }
}

// ---------------- K1: scores via bf16 MFMA, no LDS, no barriers.
// Block = 256 threads = 4 waves x 16 nodes. Wave computes all 64 attn cols
// for its 16 nodes: 4 N-tiles of 16x16x32, K fully unrolled (8 steps).
// A-frags loaded directly from x (fp32->bf16 in-register); B-frags from the
// prep-built fragment-ordered bf16 table (L2-resident, coalesced 16B loads).
__global__ __launch_bounds__(256) void k_scores(const float* __restrict__ x,
                                                const unsigned short* __restrict__ Wbf,
                                                const float* __restrict__ b_att,
                                                const float* __restrict__ ctx,
                                                float* __restrict__ scores) {
    const int t = threadIdx.x;
    const int wave = t >> 6;
    const int lane = t & 63;
    const int quad = lane >> 4;
    const int lcol = lane & 15;
    const int base = blockIdx.x * 64 + wave * 16;

    const int arow = base + lcol;               // node this lane loads A for
    const bool avalid = arow < N_NODES;
    const float* xr = x + (size_t)arow * DIM + quad * 8;

    floatx4 acc[4];
#pragma unroll
    for (int nt = 0; nt < 4; nt++) acc[nt] = (floatx4)0.f;

#pragma unroll
    for (int s = 0; s < 8; s++) {
        float4 a0 = make_float4(0.f, 0.f, 0.f, 0.f), a1 = a0;
        if (avalid) {
            a0 = *(const float4*)(xr + s * 32);
            a1 = *(const float4*)(xr + s * 32 + 4);
        }
        short8 af;
        af[0] = (short)f2bf(a0.x); af[1] = (short)f2bf(a0.y);
        af[2] = (short)f2bf(a0.z); af[3] = (short)f2bf(a0.w);
        af[4] = (short)f2bf(a1.x); af[5] = (short)f2bf(a1.y);
        af[6] = (short)f2bf(a1.z); af[7] = (short)f2bf(a1.w);
#pragma unroll
        for (int nt = 0; nt < 4; nt++) {
            short8 bf = *(const short8*)(Wbf + ((size_t)((s * 4 + nt) * 64) + lane) * 8);
            acc[nt] = __builtin_amdgcn_mfma_f32_16x16x32_bf16(af, bf, acc[nt], 0, 0, 0);
        }
    }

    // epilogue: lane holds D[m=quad*4+r][n=lcol] for each nt (col = nt*16+lcol)
    float v[4] = {0.f, 0.f, 0.f, 0.f};
#pragma unroll
    for (int nt = 0; nt < 4; nt++) {
        float cv = ctx[nt * 16 + lcol];
        float bv = b_att[nt * 16 + lcol];
#pragma unroll
        for (int r = 0; r < 4; r++) v[r] += cv * tanhf(acc[nt][r] + bv);
    }
#pragma unroll
    for (int r = 0; r < 4; r++) {
        v[r] += __shfl_xor(v[r], 1);
        v[r] += __shfl_xor(v[r], 2);
        v[r] += __shfl_xor(v[r], 4);
        v[r] += __shfl_xor(v[r], 8);
    }
    if (lcol == 0) {
        int node = base + quad * 4;
#pragma unroll
        for (int r = 0; r < 4; r++)
            if (node + r < N_NODES) scores[node + r] = v[r];
    }
}

// ---------------- K2: per-segment stable softmax, w written in-place into scores
__global__ __launch_bounds__(256) void k_segsoftmax(float* __restrict__ scores,
                                                    const int* __restrict__ seg_start) {
    int g = blockIdx.x;
    int s0 = seg_start[g], s1 = seg_start[g + 1];
    int t = threadIdx.x;
    __shared__ float red[256];

    float m = -INFINITY;
    for (int i = s0 + t; i < s1; i += 256) m = fmaxf(m, scores[i]);
    red[t] = m;
    __syncthreads();
    for (int off = 128; off > 0; off >>= 1) {
        if (t < off) red[t] = fmaxf(red[t], red[t + off]);
        __syncthreads();
    }
    m = red[0];
    __syncthreads();

    float sum = 0.f;
    for (int i = s0 + t; i < s1; i += 256) sum += __expf(scores[i] - m);
    red[t] = sum;
    __syncthreads();
    for (int off = 128; off > 0; off >>= 1) {
        if (t < off) red[t] += red[t + off];
        __syncthreads();
    }
    float inv = 1.f / (red[0] + 1e-8f);
    __syncthreads();

    for (int i = s0 + t; i < s1; i += 256) scores[i] = __expf(scores[i] - m) * inv;
}

// ---------------- K3: linear-streaming weighted pooling with atomic flush.
// Block streams PNB contiguous nodes; wave grp handles nodes n0+grp, +4...
// Segment id is wave-uniform; accumulate in registers, atomicAdd to pooled
// only on segment transition (~1 flush/wave since batch is sorted).
__global__ __launch_bounds__(256) void k_pool(const float* __restrict__ x,
                                              const float* __restrict__ w,   // = scores
                                              const int* __restrict__ batch,
                                              float* __restrict__ pooled) {
    int t = threadIdx.x;
    int grp = t >> 6;
    int c = (t & 63) * 4;
    int n0 = blockIdx.x * PNB;
    int n1 = min(n0 + PNB, N_NODES);
    int i0 = n0 + grp;
    if (i0 >= n1) return;

    int cur = batch[i0];
    float4 acc = make_float4(0.f, 0.f, 0.f, 0.f);
    for (int i = i0; i < n1; i += 4) {
        int b = batch[i];
        if (b != cur) {
            float* p = pooled + (size_t)cur * DIM + c;
            atomicAdd(p + 0, acc.x);
            atomicAdd(p + 1, acc.y);
            atomicAdd(p + 2, acc.z);
            atomicAdd(p + 3, acc.w);
            acc = make_float4(0.f, 0.f, 0.f, 0.f);
            cur = b;
        }
        float wi = w[i];
        float4 v = *(const float4*)(x + (size_t)i * DIM + c);
        acc.x += wi * v.x;
        acc.y += wi * v.y;
        acc.z += wi * v.z;
        acc.w += wi * v.w;
    }
    float* p = pooled + (size_t)cur * DIM + c;
    atomicAdd(p + 0, acc.x);
    atomicAdd(p + 1, acc.y);
    atomicAdd(p + 2, acc.z);
    atomicAdd(p + 3, acc.w);
}

// ---------------- K4: out = pooled @ W_out^T + b_out
__global__ __launch_bounds__(256) void k_out(const float* __restrict__ pooled,
                                             const float* __restrict__ WtOut,  // [d][o]
                                             const float* __restrict__ b_out,
                                             float* __restrict__ out) {
    int g = blockIdx.x;
    int t = threadIdx.x;
    __shared__ float p[256];
    p[t] = pooled[g * DIM + t];
    __syncthreads();
    float acc = b_out[t];
#pragma unroll 4
    for (int d = 0; d < DIM; d++) acc += p[d] * WtOut[d * DIM + t];
    out[g * DIM + t] = acc;
}

extern "C" void kernel_launch(void* const* d_in, const int* in_sizes, int n_in,
                              void* d_out, int out_size, void* d_ws, size_t ws_size,
                              hipStream_t stream) {
    (void)in_sizes; (void)n_in; (void)out_size; (void)ws_size;
    const float* x     = (const float*)d_in[0];
    const int*   batch = (const int*)d_in[1];
    const float* W_att = (const float*)d_in[2];
    const float* b_att = (const float*)d_in[3];
    const float* ctx   = (const float*)d_in[4];
    const float* W_out = (const float*)d_in[5];
    const float* b_out = (const float*)d_in[6];
    float* out = (float*)d_out;

    // workspace layout (floats)
    float* scores  = (float*)d_ws;                 // 500032 (doubles as w)
    float* pooled  = scores + 500032;              // 131072
    float* Wt_out  = pooled + 131072;              // 65536
    unsigned short* Wbf = (unsigned short*)(Wt_out + 65536);  // 16384 shorts (8192 floats)
    int* seg_start = (int*)(Wt_out + 65536 + 8192);           // 513 ints

    hipMemsetAsync(pooled, 0, (size_t)NG * DIM * sizeof(float), stream);
    k_prep<<<dim3(DIM), dim3(256), 0, stream>>>(W_att, W_out, Wt_out, Wbf);
    k_offsets<<<dim3((N_NODES + 255) / 256), dim3(256), 0, stream>>>(batch, seg_start);
    k_scores<<<dim3((N_NODES + 63) / 64), dim3(256), 0, stream>>>(x, Wbf, b_att, ctx, scores);
    k_segsoftmax<<<dim3(NG), dim3(256), 0, stream>>>(scores, seg_start);
    k_pool<<<dim3((N_NODES + PNB - 1) / PNB), dim3(256), 0, stream>>>(x, scores, batch, pooled);
    k_out<<<dim3(NG), dim3(256), 0, stream>>>(pooled, Wt_out, b_out, out);
}